// Round 1
// baseline (357.972 us; speedup 1.0000x reference)
//
#include <hip/hip_runtime.h>

// Problem constants (from reference setup_inputs):
//   features: (B=4, C=1024, 14, 14) fp32
//   H_Box:    (4, 16, 6) fp32   O_Box: (4, 16, 6) fp32
//   im_h=480, im_w=640 (int scalars)
// Outputs (flat concat, fp32):
//   H_Node   (4,16,1024,7,7)      = 3,211,264   @ 0
//   O_Node   (4,16,1024,7,7)      = 3,211,264   @ 3,211,264
//   H_O_Node (4,16,16,1024,7,7)   = 51,380,224  @ 6,422,528
//   geometry (4,16,16,9)          = 9,216       @ 57,802,752
//   h_ratio  (4,16)               = 64          @ 57,811,968
//   o_ratio  (4,16)               = 64          @ 57,812,032
//   ho_ratio (4,16,16)            = 1,024       @ 57,812,096

#define C_CH   1024
#define HW     14
#define OUTS   7
#define TILE   (C_CH * OUTS * OUTS)   // 50176 elems per roi
#define OFF_O  3211264
#define OFF_U  6422528
#define OFF_G  57802752
#define OFF_HR 57811968
#define OFF_OR 57812032
#define OFF_UR 57812096

// Main RoI-align kernel. blockIdx.y = global roi id r in [0,1152):
//   r <  64  : H roi (b = r/16, p = r%16)
//   r < 128  : O roi
//   else     : union roi u = r-128 = ((b*16)+h)*16+o
// blockIdx.x in [0,49): each block's 256 threads write 4 elems each
// (1024 elems) of the roi's 50176-elem (C,7,7) tile -> float4 stores.
__global__ __launch_bounds__(256) void roi_align_kernel(
    const float* __restrict__ feat,
    const float* __restrict__ HBox,
    const float* __restrict__ OBox,
    const int* __restrict__ im_h_p,
    const int* __restrict__ im_w_p,
    float* __restrict__ out)
{
    const int r = blockIdx.y;
    const float im_w = (float)(*im_w_p);
    const float im_h = (float)(*im_h_p);
    // total box->feature scale: (224/im) * (1/16)
    const float scx = (224.0f / im_w) * (1.0f / 16.0f);
    const float scy = (224.0f / im_h) * (1.0f / 16.0f);

    int b;
    float x1, y1, x2, y2;
    float* outBase;
    if (r < 64) {
        b = r >> 4;
        const float* bx = HBox + r * 6;
        x1 = bx[0]; y1 = bx[1]; x2 = bx[2]; y2 = bx[3];
        outBase = out + (size_t)r * TILE;
    } else if (r < 128) {
        const int rr = r - 64;
        b = rr >> 4;
        const float* bx = OBox + rr * 6;
        x1 = bx[0]; y1 = bx[1]; x2 = bx[2]; y2 = bx[3];
        outBase = out + OFF_O + (size_t)rr * TILE;
    } else {
        const int u = r - 128;           // u = b*256 + h*16 + o
        b = u >> 8;
        const int h = (u >> 4) & 15;
        const int o = u & 15;
        const float* hb = HBox + (b * 16 + h) * 6;
        const float* ob = OBox + (b * 16 + o) * 6;
        x1 = fminf(ob[0], hb[0]);
        y1 = fminf(ob[1], hb[1]);
        x2 = fmaxf(ob[2], hb[2]);
        y2 = fmaxf(ob[3], hb[3]);
        outBase = out + OFF_U + (size_t)u * TILE;
    }

    // scaled roi params
    const float bx1 = x1 * scx;
    const float by1 = y1 * scy;
    const float bw = (x2 * scx - bx1) * (1.0f / OUTS);
    const float bh = (y2 * scy - by1) * (1.0f / OUTS);

    const float* fB = feat + (size_t)b * (C_CH * HW * HW);

    const int e0 = (blockIdx.x * 256 + threadIdx.x) * 4;
    float4 res;
    float* rp = &res.x;
#pragma unroll
    for (int k = 0; k < 4; ++k) {
        const int e = e0 + k;
        const int c = e / 49;
        const int pos = e - c * 49;
        const int oy = pos / 7;
        const int ox = pos - oy * 7;

        float X = bx1 + ((float)ox + 0.5f) * bw;
        float Y = by1 + ((float)oy + 0.5f) * bh;
        X = fminf(fmaxf(X, 0.0f), (float)(HW - 1));
        Y = fminf(fmaxf(Y, 0.0f), (float)(HW - 1));
        const float fx0 = floorf(X);
        const float fy0 = floorf(Y);
        const int x0 = (int)fx0;          // already in [0,13]
        const int y0 = (int)fy0;
        const int x1i = min(x0 + 1, HW - 1);
        const int y1i = min(y0 + 1, HW - 1);
        const float lx = X - fx0;
        const float ly = Y - fy0;

        const float* fp = fB + c * (HW * HW);
        const float f00 = fp[y0 * HW + x0];
        const float f01 = fp[y0 * HW + x1i];
        const float f10 = fp[y1i * HW + x0];
        const float f11 = fp[y1i * HW + x1i];
        // match reference expression shape for bit-closeness
        rp[k] = f00 * (1.0f - ly) * (1.0f - lx)
              + f01 * (1.0f - ly) * lx
              + f10 * ly * (1.0f - lx)
              + f11 * ly * lx;
    }
    *(float4*)(outBase + e0) = res;
}

// Pairwise geometry + ratios. 1024 threads total (4 blocks x 256).
__global__ __launch_bounds__(256) void geom_kernel(
    const float* __restrict__ HBox,
    const float* __restrict__ OBox,
    const int* __restrict__ im_h_p,
    const int* __restrict__ im_w_p,
    float* __restrict__ geo,
    float* __restrict__ h_ratio,
    float* __restrict__ o_ratio,
    float* __restrict__ ho_ratio)
{
    const int p = blockIdx.x * 256 + threadIdx.x;   // 0..1023
    if (p >= 1024) return;
    const float im_w = (float)(*im_w_p);
    const float im_h = (float)(*im_h_p);
    const float im_area = im_h * im_w;

    const int b = p >> 8;
    const int h = (p >> 4) & 15;
    const int o = p & 15;
    const float* hb = HBox + (b * 16 + h) * 6;
    const float* ob = OBox + (b * 16 + o) * 6;
    const float hx1 = hb[0], hy1 = hb[1], hx2 = hb[2], hy2 = hb[3];
    const float ox1 = ob[0], oy1 = ob[1], ox2 = ob[2], oy2 = ob[3];

    const float h_cx = (hx1 + hx2) * 0.5f, h_cy = (hy1 + hy2) * 0.5f;
    const float h_w = hx2 - hx1, h_h = hy2 - hy1;
    const float o_cx = (ox1 + ox2) * 0.5f, o_cy = (oy1 + oy2) * 0.5f;
    const float o_w = ox2 - ox1, o_h = oy2 - oy1;

    const float dxc = h_cx - o_cx;
    const float dyc = h_cy - o_cy;
    const float adx = fabsf(dxc), ady = fabsf(dyc);

    const float d_x = adx / h_w * 100.0f;
    const float d_y = ady / h_h * 100.0f;
    const float d_xy = sqrtf(dxc * dxc + dyc * dyc) / (h_w + h_h) * 100.0f;
    const float dx_ratio = adx / im_w * 100.0f;
    const float dy_ratio = ady / im_h * 100.0f;
    const float det_y = (ady > 1e-5f) ? dyc : ((dyc > 0.0f) ? 1e-5f : -1e-5f);
    const float angle = atanf(dxc / det_y);
    const float area_scale = (o_w * o_h) / (h_w * h_h);
    const float o_scale = o_h / o_w;

    const float ix1 = fmaxf(hx1, ox1), iy1 = fmaxf(hy1, oy1);
    const float ix2 = fminf(hx2, ox2), iy2 = fminf(hy2, oy2);
    const float inter = fmaxf(ix2 - ix1, 0.0f) * fmaxf(iy2 - iy1, 0.0f);
    const float uni = h_w * h_h + o_w * o_h - inter;
    const float iou = (inter > 0.0f) ? inter / uni : 0.0f;

    float* g = geo + (size_t)p * 9;
    g[0] = d_x; g[1] = d_y; g[2] = d_xy;
    g[3] = dx_ratio; g[4] = dy_ratio; g[5] = angle;
    g[6] = area_scale; g[7] = o_scale; g[8] = iou;

    const float ux1 = fminf(ox1, hx1), uy1 = fminf(oy1, hy1);
    const float ux2 = fmaxf(ox2, hx2), uy2 = fmaxf(oy2, hy2);
    ho_ratio[p] = (ux2 - ux1) * (uy2 - uy1) / im_area * 100.0f;

    if (p < 64) {
        const float* hb2 = HBox + p * 6;
        h_ratio[p] = (hb2[2] - hb2[0]) * (hb2[3] - hb2[1]) / im_area * 100.0f;
        const float* ob2 = OBox + p * 6;
        o_ratio[p] = (ob2[2] - ob2[0]) * (ob2[3] - ob2[1]) / im_area * 100.0f;
    }
}

extern "C" void kernel_launch(void* const* d_in, const int* in_sizes, int n_in,
                              void* d_out, int out_size, void* d_ws, size_t ws_size,
                              hipStream_t stream) {
    const float* feat = (const float*)d_in[0];
    const float* HBox = (const float*)d_in[1];
    const float* OBox = (const float*)d_in[2];
    const int* im_h = (const int*)d_in[3];
    const int* im_w = (const int*)d_in[4];
    float* out = (float*)d_out;

    // 1152 rois (64 H + 64 O + 1024 union) x 49 blocks x 256 thr x 4 elem
    dim3 grid(49, 1152);
    roi_align_kernel<<<grid, 256, 0, stream>>>(feat, HBox, OBox, im_h, im_w, out);

    geom_kernel<<<4, 256, 0, stream>>>(HBox, OBox, im_h, im_w,
                                       out + OFF_G, out + OFF_HR,
                                       out + OFF_OR, out + OFF_UR);
}

// Round 2
// 242.596 us; speedup vs baseline: 1.4756x; 1.4756x over previous
//
#include <hip/hip_runtime.h>

// features: (B=4, C=1024, 14, 14) fp32; H_Box/O_Box: (4,16,6); im_h=480, im_w=640
// Outputs (flat concat, fp32):
//   H_Node   (4,16,1024,7,7)      = 3,211,264   @ 0
//   O_Node   (4,16,1024,7,7)      = 3,211,264   @ 3,211,264
//   H_O_Node (4,16,16,1024,7,7)   = 51,380,224  @ 6,422,528
//   geometry (4,16,16,9)          = 9,216       @ 57,802,752
//   h_ratio  (4,16)               = 64          @ 57,811,968
//   o_ratio  (4,16)               = 64          @ 57,812,032
//   ho_ratio (4,16,16)            = 1,024       @ 57,812,096

#define C_CH   1024
#define HW     14
#define PLANE  196              // 14*14 floats per channel plane
#define OUTS   7
#define TILE   (C_CH * OUTS * OUTS)   // 50176 elems per roi
#define OFF_O  3211264
#define OFF_U  6422528
#define OFF_G  57802752
#define OFF_HR 57811968
#define OFF_OR 57812032
#define OFF_UR 57812096

#define CH_PER_BLK   32         // channels staged per block (25,088 B LDS)
#define ROI_PER_BLK  8          // rois sharing one staging (288 % 8 == 0 -> same b)
#define CH_PER_WAVE  8          // 4 waves x 8 = 32

// Global roi index g in [0,1152), ordered by batch: b = g/288, j = g%288:
//   j <  16 : H roi (b, j)
//   j <  32 : O roi (b, j-16)
//   else    : union roi u = j-32 -> h = u>>4, o = u&15
//
// grid = (32 channel-groups, 144 roi-groups), block = 256.
// Stage 32 planes -> LDS (coalesced float4; 196 = 49*4 so float4s never
// straddle planes -> flat copy, no index math). Lane = output position
// (49 active of 64). Desc (off, w00..w11) in registers per roi.
// Inner loop per channel: 4 ds_read_b32 at imm offsets + 4 fma + 1 store.
__global__ __launch_bounds__(256) void roi_align_kernel(
    const float* __restrict__ feat,
    const float* __restrict__ HBox,
    const float* __restrict__ OBox,
    const int* __restrict__ im_h_p,
    const int* __restrict__ im_w_p,
    float* __restrict__ out)
{
    __shared__ float lds[CH_PER_BLK * PLANE];   // 6272 floats

    const int c0 = blockIdx.x * CH_PER_BLK;
    const int g0 = blockIdx.y * ROI_PER_BLK;
    const int b  = g0 / 288;                    // block-uniform

    // ---- stage 32 contiguous planes, fully coalesced ----
    {
        const float4* g4 = (const float4*)(feat + ((size_t)b * C_CH + c0) * PLANE);
        float4* l4 = (float4*)lds;
        for (int i = threadIdx.x; i < (CH_PER_BLK * PLANE / 4); i += 256)
            l4[i] = g4[i];
    }
    __syncthreads();

    const int lane = threadIdx.x & 63;
    const int wave = threadIdx.x >> 6;
    if (lane >= 49) return;                     // no further block-wide syncs

    const int pos = lane;
    const int oy = pos / 7;
    const int ox = pos - oy * 7;

    const float im_w = (float)(*im_w_p);
    const float im_h = (float)(*im_h_p);
    const float scx = (224.0f / im_w) * (1.0f / 16.0f);
    const float scy = (224.0f / im_h) * (1.0f / 16.0f);

    const float* ldw = lds + (wave * CH_PER_WAVE) * PLANE;

    for (int ri = 0; ri < ROI_PER_BLK; ++ri) {
        const int g = g0 + ri;
        const int j = g - b * 288;              // block-uniform branch below

        float x1, y1, x2, y2;
        size_t outBase;
        if (j < 16) {
            const float* bx = HBox + (b * 16 + j) * 6;
            x1 = bx[0]; y1 = bx[1]; x2 = bx[2]; y2 = bx[3];
            outBase = (size_t)(b * 16 + j) * TILE;
        } else if (j < 32) {
            const float* bx = OBox + (b * 16 + (j - 16)) * 6;
            x1 = bx[0]; y1 = bx[1]; x2 = bx[2]; y2 = bx[3];
            outBase = OFF_O + (size_t)(b * 16 + (j - 16)) * TILE;
        } else {
            const int u = j - 32;
            const float* hb = HBox + (b * 16 + (u >> 4)) * 6;
            const float* ob = OBox + (b * 16 + (u & 15)) * 6;
            x1 = fminf(ob[0], hb[0]);
            y1 = fminf(ob[1], hb[1]);
            x2 = fmaxf(ob[2], hb[2]);
            y2 = fmaxf(ob[3], hb[3]);
            outBase = OFF_U + (size_t)(b * 256 + u) * TILE;
        }

        // bilinear descriptor (once per roi, loop-invariant registers)
        const float bx1 = x1 * scx;
        const float by1 = y1 * scy;
        const float bw = (x2 * scx - bx1) * (1.0f / OUTS);
        const float bh = (y2 * scy - by1) * (1.0f / OUTS);
        float X = bx1 + ((float)ox + 0.5f) * bw;
        float Y = by1 + ((float)oy + 0.5f) * bh;
        X = fminf(fmaxf(X, 0.0f), (float)(HW - 1));
        Y = fminf(fmaxf(Y, 0.0f), (float)(HW - 1));
        // clamp base to <=12 so x1i=x0+1 always; X==13 -> lx=1 -> weight flows
        // to f01 which equals reference's clamped f00. Bit-equivalent result.
        const int x0 = min((int)floorf(X), HW - 2);
        const int y0 = min((int)floorf(Y), HW - 2);
        const float lx = X - (float)x0;
        const float ly = Y - (float)y0;
        const float w00 = (1.0f - ly) * (1.0f - lx);
        const float w01 = (1.0f - ly) * lx;
        const float w10 = ly * (1.0f - lx);
        const float w11 = ly * lx;
        const int off = y0 * HW + x0;

        const float* lp = ldw + off;
        float* op = out + outBase + (size_t)(c0 + wave * CH_PER_WAVE) * 49 + pos;
#pragma unroll
        for (int k = 0; k < CH_PER_WAVE; ++k) {
            const float f00 = lp[0];
            const float f01 = lp[1];
            const float f10 = lp[HW];
            const float f11 = lp[HW + 1];
            *op = f00 * w00 + f01 * w01 + f10 * w10 + f11 * w11;
            lp += PLANE;
            op += 49;
        }
    }
}

// Pairwise geometry + ratios. 1024 threads total (4 blocks x 256).
__global__ __launch_bounds__(256) void geom_kernel(
    const float* __restrict__ HBox,
    const float* __restrict__ OBox,
    const int* __restrict__ im_h_p,
    const int* __restrict__ im_w_p,
    float* __restrict__ geo,
    float* __restrict__ h_ratio,
    float* __restrict__ o_ratio,
    float* __restrict__ ho_ratio)
{
    const int p = blockIdx.x * 256 + threadIdx.x;   // 0..1023
    if (p >= 1024) return;
    const float im_w = (float)(*im_w_p);
    const float im_h = (float)(*im_h_p);
    const float im_area = im_h * im_w;

    const int b = p >> 8;
    const int h = (p >> 4) & 15;
    const int o = p & 15;
    const float* hb = HBox + (b * 16 + h) * 6;
    const float* ob = OBox + (b * 16 + o) * 6;
    const float hx1 = hb[0], hy1 = hb[1], hx2 = hb[2], hy2 = hb[3];
    const float ox1 = ob[0], oy1 = ob[1], ox2 = ob[2], oy2 = ob[3];

    const float h_cx = (hx1 + hx2) * 0.5f, h_cy = (hy1 + hy2) * 0.5f;
    const float h_w = hx2 - hx1, h_h = hy2 - hy1;
    const float o_cx = (ox1 + ox2) * 0.5f, o_cy = (oy1 + oy2) * 0.5f;
    const float o_w = ox2 - ox1, o_h = oy2 - oy1;

    const float dxc = h_cx - o_cx;
    const float dyc = h_cy - o_cy;
    const float adx = fabsf(dxc), ady = fabsf(dyc);

    const float d_x = adx / h_w * 100.0f;
    const float d_y = ady / h_h * 100.0f;
    const float d_xy = sqrtf(dxc * dxc + dyc * dyc) / (h_w + h_h) * 100.0f;
    const float dx_ratio = adx / im_w * 100.0f;
    const float dy_ratio = ady / im_h * 100.0f;
    const float det_y = (ady > 1e-5f) ? dyc : ((dyc > 0.0f) ? 1e-5f : -1e-5f);
    const float angle = atanf(dxc / det_y);
    const float area_scale = (o_w * o_h) / (h_w * h_h);
    const float o_scale = o_h / o_w;

    const float ix1 = fmaxf(hx1, ox1), iy1 = fmaxf(hy1, oy1);
    const float ix2 = fminf(hx2, ox2), iy2 = fminf(hy2, oy2);
    const float inter = fmaxf(ix2 - ix1, 0.0f) * fmaxf(iy2 - iy1, 0.0f);
    const float uni = h_w * h_h + o_w * o_h - inter;
    const float iou = (inter > 0.0f) ? inter / uni : 0.0f;

    float* g = geo + (size_t)p * 9;
    g[0] = d_x; g[1] = d_y; g[2] = d_xy;
    g[3] = dx_ratio; g[4] = dy_ratio; g[5] = angle;
    g[6] = area_scale; g[7] = o_scale; g[8] = iou;

    const float ux1 = fminf(ox1, hx1), uy1 = fminf(oy1, hy1);
    const float ux2 = fmaxf(ox2, hx2), uy2 = fmaxf(oy2, hy2);
    ho_ratio[p] = (ux2 - ux1) * (uy2 - uy1) / im_area * 100.0f;

    if (p < 64) {
        const float* hb2 = HBox + p * 6;
        h_ratio[p] = (hb2[2] - hb2[0]) * (hb2[3] - hb2[1]) / im_area * 100.0f;
        const float* ob2 = OBox + p * 6;
        o_ratio[p] = (ob2[2] - ob2[0]) * (ob2[3] - ob2[1]) / im_area * 100.0f;
    }
}

extern "C" void kernel_launch(void* const* d_in, const int* in_sizes, int n_in,
                              void* d_out, int out_size, void* d_ws, size_t ws_size,
                              hipStream_t stream) {
    const float* feat = (const float*)d_in[0];
    const float* HBox = (const float*)d_in[1];
    const float* OBox = (const float*)d_in[2];
    const int* im_h = (const int*)d_in[3];
    const int* im_w = (const int*)d_in[4];
    float* out = (float*)d_out;

    // 32 channel-groups x 144 roi-groups (8 rois each, same batch b)
    dim3 grid(32, 144);
    roi_align_kernel<<<grid, 256, 0, stream>>>(feat, HBox, OBox, im_h, im_w, out);

    geom_kernel<<<4, 256, 0, stream>>>(HBox, OBox, im_h, im_w,
                                       out + OFF_G, out + OFF_HR,
                                       out + OFF_OR, out + OFF_UR);
}

// Round 3
// 240.349 us; speedup vs baseline: 1.4894x; 1.0093x over previous
//
#include <hip/hip_runtime.h>

// features: (B=4, C=1024, 14, 14) fp32; H_Box/O_Box: (4,16,6); im_h=480, im_w=640
// Outputs (flat concat, fp32):
//   H_Node   (4,16,1024,7,7)      = 3,211,264   @ 0
//   O_Node   (4,16,1024,7,7)      = 3,211,264   @ 3,211,264
//   H_O_Node (4,16,16,1024,7,7)   = 51,380,224  @ 6,422,528
//   geometry (4,16,16,9)          = 9,216       @ 57,802,752
//   h_ratio  (4,16)               = 64          @ 57,811,968
//   o_ratio  (4,16)               = 64          @ 57,812,032
//   ho_ratio (4,16,16)            = 1,024       @ 57,812,096

#define C_CH   1024
#define HW     14
#define PLANE  196              // 14*14 floats per channel plane
#define OUTS   7
#define TILE   (C_CH * OUTS * OUTS)   // 50176 elems per roi
#define OFF_O  3211264
#define OFF_U  6422528
#define OFF_G  57802752
#define OFF_HR 57811968
#define OFF_OR 57812032
#define OFF_UR 57812096

#define CH_PER_BLK   32         // channels staged per block (25,088 B LDS)
#define ROI_PER_BLK  16         // rois sharing one staging (288 % 16 == 0 -> same b)
#define CH_PER_WAVE  8          // 4 waves x 8 = 32

// grid = (32 channel-groups, 72 roi-groups), block = 256.
// Stage 32 planes -> LDS (coalesced float4; 196 = 49*4 so float4s never
// straddle planes). Lane = output position (49 active of 64); wave owns 8
// channels; block loops 16 rois over the staged planes.
// Per channel: taps at dword offsets {0,1,14,15} from a per-channel base ->
// compiler merges into 2x ds_read2_b32; stores use immediate offsets op[49*k].
__global__ __launch_bounds__(256) void roi_align_kernel(
    const float* __restrict__ feat,
    const float* __restrict__ HBox,
    const float* __restrict__ OBox,
    const int* __restrict__ im_h_p,
    const int* __restrict__ im_w_p,
    float* __restrict__ out)
{
    __shared__ float lds[CH_PER_BLK * PLANE];   // 6272 floats

    const int c0 = blockIdx.x * CH_PER_BLK;
    const int g0 = blockIdx.y * ROI_PER_BLK;
    const int b  = g0 / 288;                    // block-uniform

    // ---- stage 32 contiguous planes, fully coalesced ----
    {
        const float4* g4 = (const float4*)(feat + ((size_t)b * C_CH + c0) * PLANE);
        float4* l4 = (float4*)lds;
        for (int i = threadIdx.x; i < (CH_PER_BLK * PLANE / 4); i += 256)
            l4[i] = g4[i];
    }
    __syncthreads();

    const int lane = threadIdx.x & 63;
    const int wave = threadIdx.x >> 6;
    if (lane >= 49) return;                     // no further block-wide syncs

    const int pos = lane;
    const int oy = pos / 7;
    const int ox = pos - oy * 7;

    const float im_w = (float)(*im_w_p);
    const float im_h = (float)(*im_h_p);
    const float scx = (224.0f / im_w) * (1.0f / 16.0f);
    const float scy = (224.0f / im_h) * (1.0f / 16.0f);

    const float* ldw = lds + (wave * CH_PER_WAVE) * PLANE;
    const int cw = c0 + wave * CH_PER_WAVE;     // first channel this wave owns

    for (int ri = 0; ri < ROI_PER_BLK; ++ri) {
        const int g = g0 + ri;
        const int j = g - b * 288;              // block-uniform branch below

        float x1, y1, x2, y2;
        size_t outBase;
        if (j < 16) {
            const float* bx = HBox + (b * 16 + j) * 6;
            x1 = bx[0]; y1 = bx[1]; x2 = bx[2]; y2 = bx[3];
            outBase = (size_t)(b * 16 + j) * TILE;
        } else if (j < 32) {
            const float* bx = OBox + (b * 16 + (j - 16)) * 6;
            x1 = bx[0]; y1 = bx[1]; x2 = bx[2]; y2 = bx[3];
            outBase = OFF_O + (size_t)(b * 16 + (j - 16)) * TILE;
        } else {
            const int u = j - 32;
            const float* hb = HBox + (b * 16 + (u >> 4)) * 6;
            const float* ob = OBox + (b * 16 + (u & 15)) * 6;
            x1 = fminf(ob[0], hb[0]);
            y1 = fminf(ob[1], hb[1]);
            x2 = fmaxf(ob[2], hb[2]);
            y2 = fmaxf(ob[3], hb[3]);
            outBase = OFF_U + (size_t)(b * 256 + u) * TILE;
        }

        // bilinear descriptor (once per roi, loop-invariant registers)
        const float bx1 = x1 * scx;
        const float by1 = y1 * scy;
        const float bw = (x2 * scx - bx1) * (1.0f / OUTS);
        const float bh = (y2 * scy - by1) * (1.0f / OUTS);
        float X = bx1 + ((float)ox + 0.5f) * bw;
        float Y = by1 + ((float)oy + 0.5f) * bh;
        X = fminf(fmaxf(X, 0.0f), (float)(HW - 1));
        Y = fminf(fmaxf(Y, 0.0f), (float)(HW - 1));
        // clamp base to <=12 so x1i=x0+1 always; X==13 -> lx=1 -> weight flows
        // to f01 which equals reference's clamped f00. Bit-equivalent result.
        const int x0 = min((int)floorf(X), HW - 2);
        const int y0 = min((int)floorf(Y), HW - 2);
        const float lx = X - (float)x0;
        const float ly = Y - (float)y0;
        const float w00 = (1.0f - ly) * (1.0f - lx);
        const float w01 = (1.0f - ly) * lx;
        const float w10 = ly * (1.0f - lx);
        const float w11 = ly * lx;
        const int off = y0 * HW + x0;

        const float* lp = ldw + off;
        float* op = out + outBase + (size_t)cw * 49 + pos;
#pragma unroll
        for (int k = 0; k < CH_PER_WAVE; ++k) {
            // dword offsets {0,1,14,15} from per-channel base -> 2x ds_read2_b32
            const float f00 = lp[0];
            const float f01 = lp[1];
            const float f10 = lp[HW];
            const float f11 = lp[HW + 1];
            op[49 * k] = f00 * w00 + f01 * w01 + f10 * w10 + f11 * w11;
            lp += PLANE;
        }
    }
}

// Pairwise geometry + ratios. 1024 threads total (4 blocks x 256).
__global__ __launch_bounds__(256) void geom_kernel(
    const float* __restrict__ HBox,
    const float* __restrict__ OBox,
    const int* __restrict__ im_h_p,
    const int* __restrict__ im_w_p,
    float* __restrict__ geo,
    float* __restrict__ h_ratio,
    float* __restrict__ o_ratio,
    float* __restrict__ ho_ratio)
{
    const int p = blockIdx.x * 256 + threadIdx.x;   // 0..1023
    if (p >= 1024) return;
    const float im_w = (float)(*im_w_p);
    const float im_h = (float)(*im_h_p);
    const float im_area = im_h * im_w;

    const int b = p >> 8;
    const int h = (p >> 4) & 15;
    const int o = p & 15;
    const float* hb = HBox + (b * 16 + h) * 6;
    const float* ob = OBox + (b * 16 + o) * 6;
    const float hx1 = hb[0], hy1 = hb[1], hx2 = hb[2], hy2 = hb[3];
    const float ox1 = ob[0], oy1 = ob[1], ox2 = ob[2], oy2 = ob[3];

    const float h_cx = (hx1 + hx2) * 0.5f, h_cy = (hy1 + hy2) * 0.5f;
    const float h_w = hx2 - hx1, h_h = hy2 - hy1;
    const float o_cx = (ox1 + ox2) * 0.5f, o_cy = (oy1 + oy2) * 0.5f;
    const float o_w = ox2 - ox1, o_h = oy2 - oy1;

    const float dxc = h_cx - o_cx;
    const float dyc = h_cy - o_cy;
    const float adx = fabsf(dxc), ady = fabsf(dyc);

    const float d_x = adx / h_w * 100.0f;
    const float d_y = ady / h_h * 100.0f;
    const float d_xy = sqrtf(dxc * dxc + dyc * dyc) / (h_w + h_h) * 100.0f;
    const float dx_ratio = adx / im_w * 100.0f;
    const float dy_ratio = ady / im_h * 100.0f;
    const float det_y = (ady > 1e-5f) ? dyc : ((dyc > 0.0f) ? 1e-5f : -1e-5f);
    const float angle = atanf(dxc / det_y);
    const float area_scale = (o_w * o_h) / (h_w * h_h);
    const float o_scale = o_h / o_w;

    const float ix1 = fmaxf(hx1, ox1), iy1 = fmaxf(hy1, oy1);
    const float ix2 = fminf(hx2, ox2), iy2 = fminf(hy2, oy2);
    const float inter = fmaxf(ix2 - ix1, 0.0f) * fmaxf(iy2 - iy1, 0.0f);
    const float uni = h_w * h_h + o_w * o_h - inter;
    const float iou = (inter > 0.0f) ? inter / uni : 0.0f;

    float* g = geo + (size_t)p * 9;
    g[0] = d_x; g[1] = d_y; g[2] = d_xy;
    g[3] = dx_ratio; g[4] = dy_ratio; g[5] = angle;
    g[6] = area_scale; g[7] = o_scale; g[8] = iou;

    const float ux1 = fminf(ox1, hx1), uy1 = fminf(oy1, hy1);
    const float ux2 = fmaxf(ox2, hx2), uy2 = fmaxf(oy2, hy2);
    ho_ratio[p] = (ux2 - ux1) * (uy2 - uy1) / im_area * 100.0f;

    if (p < 64) {
        const float* hb2 = HBox + p * 6;
        h_ratio[p] = (hb2[2] - hb2[0]) * (hb2[3] - hb2[1]) / im_area * 100.0f;
        const float* ob2 = OBox + p * 6;
        o_ratio[p] = (ob2[2] - ob2[0]) * (ob2[3] - ob2[1]) / im_area * 100.0f;
    }
}

extern "C" void kernel_launch(void* const* d_in, const int* in_sizes, int n_in,
                              void* d_out, int out_size, void* d_ws, size_t ws_size,
                              hipStream_t stream) {
    const float* feat = (const float*)d_in[0];
    const float* HBox = (const float*)d_in[1];
    const float* OBox = (const float*)d_in[2];
    const int* im_h = (const int*)d_in[3];
    const int* im_w = (const int*)d_in[4];
    float* out = (float*)d_out;

    // 32 channel-groups x 72 roi-groups (16 rois each, same batch b)
    dim3 grid(32, 72);
    roi_align_kernel<<<grid, 256, 0, stream>>>(feat, HBox, OBox, im_h, im_w, out);

    geom_kernel<<<4, 256, 0, stream>>>(HBox, OBox, im_h, im_w,
                                       out + OFF_G, out + OFF_HR,
                                       out + OFF_OR, out + OFF_UR);
}